// Round 2
// baseline (1769.923 us; speedup 1.0000x reference)
//
#include <hip/hip_runtime.h>
#include <cstdint>
#include <cstddef>

#define N_NODES 100000
#define N_EDGES 1600000

__device__ __forceinline__ float leaky(float v) { return v > 0.f ? v : 0.2f * v; }

// ---- zero scratch (aggr + sum + sum2, contiguous) ----
__global__ __launch_bounds__(256) void k_zero(float4* __restrict__ p, int n4) {
    int i = blockIdx.x * 256 + threadIdx.x;
    int stride = gridDim.x * 256;
    for (; i < n4; i += stride) p[i] = make_float4(0.f, 0.f, 0.f, 0.f);
}

// ---- wfold[k] = sum_f W_lin_edge[k][f] * W_node_attn[64+f] ----
__global__ void k_wfold(const float* __restrict__ W_le, const float* __restrict__ W_attn,
                        float* __restrict__ wfold) {
    int k = threadIdx.x;  // 32 threads
    float s = 0.f;
    for (int fo = 0; fo < 32; ++fo) s += W_le[k * 32 + fo] * W_attn[64 + fo];
    wfold[k] = s;
}

// ---- K1: h = x@W_lin, res = x@W_res -> xout, a1 = h.w1, a2 = h.w2 ----
__global__ __launch_bounds__(256) void k_node_pre(
    const float* __restrict__ x, const float* __restrict__ W_lin,
    const float* __restrict__ W_res, const float* __restrict__ W_attn,
    float* __restrict__ h, float* __restrict__ xout,
    float* __restrict__ a1, float* __restrict__ a2) {
    __shared__ float Wl[64 * 32];
    __shared__ float Wr[64 * 32];
    __shared__ float xl[8][64];
    int tid = threadIdx.x;
    for (int i = tid; i < 64 * 32; i += 256) { Wl[i] = W_lin[i]; Wr[i] = W_res[i]; }
    __syncthreads();
    int f = tid & 31, nl = tid >> 5;
    int n = blockIdx.x * 8 + nl;   // grid divides exactly: no bounds check
    xl[nl][f]      = x[(size_t)n * 64 + f];
    xl[nl][32 + f] = x[(size_t)n * 64 + 32 + f];
    // row nl written & read by the same 32-lane group (wave-internal, lockstep)
    float hf = 0.f, rf = 0.f;
#pragma unroll
    for (int k = 0; k < 64; ++k) {
        float xv = xl[nl][k];
        hf += xv * Wl[k * 32 + f];
        rf += xv * Wr[k * 32 + f];
    }
    h[(size_t)n * 32 + f]    = hf;
    xout[(size_t)n * 32 + f] = rf;   // residual parked in output; K4 adds the rest
    float s1 = hf * W_attn[f];
    float s2 = hf * W_attn[32 + f];
#pragma unroll
    for (int m = 16; m >= 1; m >>= 1) {
        s1 += __shfl_xor(s1, m, 32);
        s2 += __shfl_xor(s2, m, 32);
    }
    if (f == 0) { a1[n] = s1; a2[n] = s2; }
}

// ---- K2: fused alpha + aggregation (unnormalized; normalize in K4) ----
// aggr[dst] += exv * cat(h_j, e);  sum[dst] += exv
__global__ __launch_bounds__(256) void k_alpha_aggr(
    const float* __restrict__ ea, const int* __restrict__ eidx,
    const float* __restrict__ a1, const float* __restrict__ a2,
    const float* __restrict__ wfold, const float* __restrict__ W_le,
    const float* __restrict__ h,
    float* __restrict__ sum, float* __restrict__ aggr) {
    __shared__ float Wle[1024];
    __shared__ float wf[32];
    __shared__ float eal[8][32];
    int tid = threadIdx.x;
    for (int i = tid; i < 1024; i += 256) Wle[i] = W_le[i];
    if (tid < 32) wf[tid] = wfold[tid];
    __syncthreads();
    int f = tid & 31, el = tid >> 5;
    int e = blockIdx.x * 8 + el;
    float v = ea[(size_t)e * 32 + f];
    eal[el][f] = v;
    int srcn = eidx[e], dstn = eidx[N_EDGES + e];
    float acc = v * wf[f];
#pragma unroll
    for (int m = 16; m >= 1; m >>= 1) acc += __shfl_xor(acc, m, 32);
    float exv = __expf(leaky(a1[dstn] + a2[srcn] + acc));
    float ef = 0.f;
#pragma unroll
    for (int k = 0; k < 32; ++k) ef += eal[el][k] * Wle[k * 32 + f];
    float hj = h[(size_t)srcn * 32 + f];
    if (f == 0) atomicAdd(&sum[dstn], exv);
    atomicAdd(&aggr[(size_t)dstn * 64 + f],      exv * hj);
    atomicAdd(&aggr[(size_t)dstn * 64 + 32 + f], exv * ef);
}

// ---- K4: normalize aggr; node_out = aggr@W_nu; xout += node_out + bias;
//          out = node_out@W_out; b1,b2 scalars ----
__global__ __launch_bounds__(256) void k_node_out(
    const float* __restrict__ aggr, const float* __restrict__ sum,
    const float* __restrict__ W_nu, const float* __restrict__ W_out_,
    const float* __restrict__ W_ea, const float* __restrict__ bias_node,
    float* __restrict__ xout, float* __restrict__ b1, float* __restrict__ b2) {
    __shared__ float Wnu[64 * 32];
    __shared__ float Wo[32 * 32];
    __shared__ float agl[8][64];
    __shared__ float nol[8][32];
    int tid = threadIdx.x;
    for (int i = tid; i < 2048; i += 256) Wnu[i] = W_nu[i];
    for (int i = tid; i < 1024; i += 256) Wo[i] = W_out_[i];
    __syncthreads();
    int f = tid & 31, nl = tid >> 5;
    int n = blockIdx.x * 8 + nl;
    float inv = 1.f / (sum[n] + 1e-16f);
    agl[nl][f]      = aggr[(size_t)n * 64 + f]      * inv;
    agl[nl][32 + f] = aggr[(size_t)n * 64 + 32 + f] * inv;
    float nf = 0.f;
#pragma unroll
    for (int k = 0; k < 64; ++k) nf += agl[nl][k] * Wnu[k * 32 + f];
    xout[(size_t)n * 32 + f] += nf + bias_node[f];
    nol[nl][f] = nf;
    float of = 0.f;
#pragma unroll
    for (int k = 0; k < 32; ++k) of += nol[nl][k] * Wo[k * 32 + f];
    float s1 = of * W_ea[f];
    float s2 = of * W_ea[32 + f];
#pragma unroll
    for (int m = 16; m >= 1; m >>= 1) {
        s1 += __shfl_xor(s1, m, 32);
        s2 += __shfl_xor(s2, m, 32);
    }
    if (f == 0) { b1[n] = s1; b2[n] = s2; }
}

// ---- K5: beta denominator (scalar-only pass) ----
__global__ __launch_bounds__(256) void k_beta(
    const int* __restrict__ eidx, const float* __restrict__ b1,
    const float* __restrict__ b2, float* __restrict__ sum2) {
    int e = blockIdx.x * 256 + threadIdx.x;
    int srcn = eidx[e], dstn = eidx[N_EDGES + e];
    float exv = __expf(leaky(b1[dstn] + b2[srcn]));
    atomicAdd(&sum2[dstn], exv);
}

// ---- K6: edge_final = beta*alpha*(cat@W_eu) + ea@W_res_edge + bias_edge ----
__global__ __launch_bounds__(256) void k_edge_final(
    const float* __restrict__ ea, const int* __restrict__ eidx,
    const float* __restrict__ W_le, const float* __restrict__ W_re,
    const float* __restrict__ W_eu, const float* __restrict__ bias_edge,
    const float* __restrict__ wfold, const float* __restrict__ h,
    const float* __restrict__ a1, const float* __restrict__ a2,
    const float* __restrict__ sum, const float* __restrict__ b1,
    const float* __restrict__ b2, const float* __restrict__ sum2,
    float* __restrict__ eout) {
    __shared__ float Wle[1024], Wre[1024], Weu[2048];
    __shared__ float wf[32], be[32];
    __shared__ float eal[8][32];
    __shared__ float cat[8][64];
    int tid = threadIdx.x;
    for (int i = tid; i < 1024; i += 256) { Wle[i] = W_le[i]; Wre[i] = W_re[i]; }
    for (int i = tid; i < 2048; i += 256) Weu[i] = W_eu[i];
    if (tid < 32) { wf[tid] = wfold[tid]; be[tid] = bias_edge[tid]; }
    __syncthreads();
    int f = tid & 31, el = tid >> 5;
    int e = blockIdx.x * 8 + el;
    float v = ea[(size_t)e * 32 + f];
    eal[el][f] = v;
    int srcn = eidx[e], dstn = eidx[N_EDGES + e];
    // recompute alpha (bit-identical arithmetic to K2)
    float acc = v * wf[f];
#pragma unroll
    for (int m = 16; m >= 1; m >>= 1) acc += __shfl_xor(acc, m, 32);
    float exv   = __expf(leaky(a1[dstn] + a2[srcn] + acc));
    float alpha = exv / (sum[dstn] + 1e-16f);
    // recompute beta (bit-identical to K5)
    float exv2 = __expf(leaky(b1[dstn] + b2[srcn]));
    float beta = exv2 / (sum2[dstn] + 1e-16f);
    float ef = 0.f, rf = 0.f;
#pragma unroll
    for (int k = 0; k < 32; ++k) {
        float w = eal[el][k];
        ef += w * Wle[k * 32 + f];
        rf += w * Wre[k * 32 + f];
    }
    float hj = h[(size_t)srcn * 32 + f];
    cat[el][f]      = hj;
    cat[el][32 + f] = ef;
    float acc2 = 0.f;
#pragma unroll
    for (int k = 0; k < 64; ++k) acc2 += cat[el][k] * Weu[k * 32 + f];
    eout[(size_t)e * 32 + f] = beta * alpha * acc2 + rf + be[f];
}

extern "C" void kernel_launch(void* const* d_in, const int* in_sizes, int n_in,
                              void* d_out, int out_size, void* d_ws, size_t ws_size,
                              hipStream_t stream) {
    const float* x         = (const float*)d_in[0];
    const int*   eidx      = (const int*)d_in[1];     // int32 per harness contract
    const float* ea        = (const float*)d_in[2];
    const float* W_lin     = (const float*)d_in[3];
    const float* W_le      = (const float*)d_in[4];
    const float* W_nattn   = (const float*)d_in[5];
    const float* W_nu      = (const float*)d_in[6];
    const float* W_out     = (const float*)d_in[7];
    const float* W_ea      = (const float*)d_in[8];
    const float* W_eu      = (const float*)d_in[9];
    const float* W_re      = (const float*)d_in[11];
    const float* bias_node = (const float*)d_in[12];
    const float* bias_edge = (const float*)d_in[13];
    const float* W_res     = (const float*)d_in[10];

    float* ws    = (float*)d_ws;
    float* aggr  = ws;                                 // N*64  (zeroed)
    float* sum   = aggr + (size_t)N_NODES * 64;        // N     (zeroed)
    float* sum2  = sum + N_NODES;                      // N     (zeroed)
    float* h     = sum2 + N_NODES;                     // N*32
    float* a1    = h + (size_t)N_NODES * 32;           // N
    float* a2    = a1 + N_NODES;                       // N
    float* b1    = a2 + N_NODES;                       // N
    float* b2    = b1 + N_NODES;                       // N
    float* wfold = b2 + N_NODES;                       // 32
    // total ~41 MB

    float* xout = (float*)d_out;                       // N*32
    float* eout = xout + (size_t)N_NODES * 32;         // E*32

    int n4 = (N_NODES * 66) / 4;  // aggr+sum+sum2 contiguous, 6.6M floats
    k_zero<<<2048, 256, 0, stream>>>((float4*)aggr, n4);
    k_wfold<<<1, 32, 0, stream>>>(W_le, W_nattn, wfold);
    k_node_pre<<<N_NODES / 8, 256, 0, stream>>>(x, W_lin, W_res, W_nattn, h, xout, a1, a2);
    k_alpha_aggr<<<N_EDGES / 8, 256, 0, stream>>>(ea, eidx, a1, a2, wfold, W_le, h, sum, aggr);
    k_node_out<<<N_NODES / 8, 256, 0, stream>>>(aggr, sum, W_nu, W_out, W_ea, bias_node, xout, b1, b2);
    k_beta<<<N_EDGES / 256, 256, 0, stream>>>(eidx, b1, b2, sum2);
    k_edge_final<<<N_EDGES / 8, 256, 0, stream>>>(ea, eidx, W_le, W_re, W_eu, bias_edge,
                                                  wfold, h, a1, a2, sum, b1, b2, sum2, eout);
}

// Round 3
// 1236.743 us; speedup vs baseline: 1.4311x; 1.4311x over previous
//
#include <hip/hip_runtime.h>
#include <cstdint>
#include <cstddef>

#define N_NODES 100000
#define N_EDGES 1600000
#define EPG 16  // edges per 32-lane group in k_edge_final

__device__ __forceinline__ float leaky(float v) { return v > 0.f ? v : 0.2f * v; }

// ---- zero aggr + sum (contiguous N*65 floats) ----
__global__ __launch_bounds__(256) void k_zero(float4* __restrict__ p, int n4) {
    int i = blockIdx.x * 256 + threadIdx.x;
    int stride = gridDim.x * 256;
    for (; i < n4; i += stride) p[i] = make_float4(0.f, 0.f, 0.f, 0.f);
}

// ---- folds: wfold = W_le@W_nattn[64:], Wnu_f = W_le@W_nu[32:], Weu_f = W_le@W_eu[32:] ----
__global__ __launch_bounds__(1024) void k_fold(
    const float* __restrict__ W_le, const float* __restrict__ W_nattn,
    const float* __restrict__ W_nu, const float* __restrict__ W_eu,
    float* __restrict__ wfold, float* __restrict__ Wnu_f, float* __restrict__ Weu_f) {
    int t = threadIdx.x;
    int k = t >> 5, f = t & 31;
    float s1 = 0.f, s2 = 0.f, s0 = 0.f;
    for (int m = 0; m < 32; ++m) {
        float w = W_le[k * 32 + m];
        s1 += w * W_nu[(32 + m) * 32 + f];
        s2 += w * W_eu[(32 + m) * 32 + f];
        s0 += w * W_nattn[64 + m];
    }
    Wnu_f[k * 32 + f] = s1;
    Weu_f[k * 32 + f] = s2;
    if (f == 0) wfold[k] = s0;
}

// ---- K1: h = x@W_lin, res = x@W_res -> xout, a1 = h.w1, a2 = h.w2 ----
__global__ __launch_bounds__(256) void k_node_pre(
    const float* __restrict__ x, const float* __restrict__ W_lin,
    const float* __restrict__ W_res, const float* __restrict__ W_attn,
    float* __restrict__ h, float* __restrict__ xout,
    float* __restrict__ a1, float* __restrict__ a2) {
    __shared__ float Wl[64 * 32];
    __shared__ float Wr[64 * 32];
    __shared__ float xl[8][64];
    int tid = threadIdx.x;
    for (int i = tid; i < 64 * 32; i += 256) { Wl[i] = W_lin[i]; Wr[i] = W_res[i]; }
    __syncthreads();
    int f = tid & 31, nl = tid >> 5;
    int n = blockIdx.x * 8 + nl;
    xl[nl][f]      = x[(size_t)n * 64 + f];
    xl[nl][32 + f] = x[(size_t)n * 64 + 32 + f];
    float hf = 0.f, rf = 0.f;
#pragma unroll
    for (int k = 0; k < 64; ++k) {
        float xv = xl[nl][k];
        hf += xv * Wl[k * 32 + f];
        rf += xv * Wr[k * 32 + f];
    }
    h[(size_t)n * 32 + f]    = hf;
    xout[(size_t)n * 32 + f] = rf;
    float s1 = hf * W_attn[f];
    float s2 = hf * W_attn[32 + f];
#pragma unroll
    for (int m = 16; m >= 1; m >>= 1) {
        s1 += __shfl_xor(s1, m, 32);
        s2 += __shfl_xor(s2, m, 32);
    }
    if (f == 0) { a1[n] = s1; a2[n] = s2; }
}

// ---- K2: alpha + RAW aggregation: aggr[dst] += exv*cat(h_j, ea); sum[dst] += exv ----
__global__ __launch_bounds__(256) void k_alpha_aggr(
    const float* __restrict__ ea, const int* __restrict__ eidx,
    const float* __restrict__ a1, const float* __restrict__ a2,
    const float* __restrict__ wfold, const float* __restrict__ h,
    float* __restrict__ sum, float* __restrict__ aggr) {
    int tid = threadIdx.x;
    int f = tid & 31, g = tid >> 5;
    int e = blockIdx.x * 8 + g;
    float v = ea[(size_t)e * 32 + f];
    int srcn = eidx[e], dstn = eidx[N_EDGES + e];
    float acc = v * wfold[f];
#pragma unroll
    for (int m = 16; m >= 1; m >>= 1) acc += __shfl_xor(acc, m, 32);
    float exv = __expf(leaky(a1[dstn] + a2[srcn] + acc));
    float hj = h[(size_t)srcn * 32 + f];
    atomicAdd(&aggr[(size_t)dstn * 64 + f],      exv * hj);
    atomicAdd(&aggr[(size_t)dstn * 64 + 32 + f], exv * v);
    if (f == 0) atomicAdd(&sum[dstn], exv);
}

// ---- K4: node_out = (aggr_h@Wnu_top + aggr_e@Wnu_f)/sum; xout += ...; b1,b2; pack q4/q2 ----
__global__ __launch_bounds__(256) void k_node_out(
    const float* __restrict__ aggr, const float* __restrict__ sum,
    const float* __restrict__ a1, const float* __restrict__ a2,
    const float* __restrict__ W_nu, const float* __restrict__ Wnu_f,
    const float* __restrict__ W_out_, const float* __restrict__ W_ea,
    const float* __restrict__ bias_node,
    float* __restrict__ xout, float4* __restrict__ q4, float2* __restrict__ q2) {
    __shared__ float Wh[1024], Wf[1024], Wo[1024];
    __shared__ float agl[8][64], nol[8][32];
    int tid = threadIdx.x;
    for (int i = tid; i < 1024; i += 256) { Wh[i] = W_nu[i]; Wf[i] = Wnu_f[i]; Wo[i] = W_out_[i]; }
    __syncthreads();
    int f = tid & 31, nl = tid >> 5;
    int n = blockIdx.x * 8 + nl;
    agl[nl][f]      = aggr[(size_t)n * 64 + f];
    agl[nl][32 + f] = aggr[(size_t)n * 64 + 32 + f];
    float nf = 0.f;
#pragma unroll
    for (int k = 0; k < 32; ++k) nf += agl[nl][k] * Wh[k * 32 + f];
#pragma unroll
    for (int k = 0; k < 32; ++k) nf += agl[nl][32 + k] * Wf[k * 32 + f];
    float inv = 1.f / (sum[n] + 1e-16f);
    nf *= inv;
    xout[(size_t)n * 32 + f] += nf + bias_node[f];
    nol[nl][f] = nf;
    float of = 0.f;
#pragma unroll
    for (int k = 0; k < 32; ++k) of += nol[nl][k] * Wo[k * 32 + f];
    float s1 = of * W_ea[f];
    float s2 = of * W_ea[32 + f];
#pragma unroll
    for (int m = 16; m >= 1; m >>= 1) {
        s1 += __shfl_xor(s1, m, 32);
        s2 += __shfl_xor(s2, m, 32);
    }
    if (f == 0) {
        q4[n] = make_float4(a1[n], s1, sum[n], 0.f);  // (a1, b1, sum, sum2=0)
        q2[n] = make_float2(a2[n], s2);               // (a2, b2)
    }
}

// ---- K5: beta denominator into q4[dst].w ----
__global__ __launch_bounds__(256) void k_beta(
    const int* __restrict__ eidx, const float* __restrict__ q4f,
    const float* __restrict__ q2f, float* __restrict__ q4w) {
    int e = blockIdx.x * 256 + threadIdx.x;
    int srcn = eidx[e], dstn = eidx[N_EDGES + e];
    float ex = __expf(leaky(q4f[(size_t)dstn * 4 + 1] + q2f[(size_t)srcn * 2 + 1]));
    atomicAdd(&q4w[(size_t)dstn * 4 + 3], ex);
}

// ---- K6: eout = alpha*beta*(h_j@Weu_top + ea@Weu_f) + ea@W_re + bias ----
__global__ __launch_bounds__(256) void k_edge_final(
    const float* __restrict__ ea, const int* __restrict__ eidx,
    const float* __restrict__ W_re, const float* __restrict__ Weu_f,
    const float* __restrict__ W_eu, const float* __restrict__ wfold,
    const float* __restrict__ h, const float4* __restrict__ q4,
    const float2* __restrict__ q2, const float* __restrict__ bias_edge,
    float* __restrict__ eout) {
    __shared__ float stage[8][2][64];
    int tid = threadIdx.x;
    int f = tid & 31, g = tid >> 5;
    // weight columns in registers (96 VGPRs/lane)
    float wre[32], wfe[32], weh[32];
#pragma unroll
    for (int k = 0; k < 32; ++k) {
        wre[k] = W_re[k * 32 + f];
        wfe[k] = Weu_f[k * 32 + f];
        weh[k] = W_eu[k * 32 + f];   // top 32 rows of W_eu
    }
    float wfv  = wfold[f];
    float bias = bias_edge[f];
    size_t base = (size_t)(blockIdx.x * 8 + g) * EPG;
    // lanes 0..15 hold src of edges base+0..15; lanes 16..31 hold dst
    int idxv = (f < 16) ? eidx[base + f] : eidx[N_EDGES + base + (f - 16)];
    int src0 = __shfl(idxv, 0, 32);
    float v0 = ea[base * 32 + f];
    float h0 = h[(size_t)src0 * 32 + f];
#pragma unroll 2
    for (int i = 0; i < EPG; ++i) {
        int srcn = __shfl(idxv, i, 32);
        int dstn = __shfl(idxv, 16 + i, 32);
        // depth-1 prefetch (clamped at chunk end)
        int ip = (i + 1 < EPG) ? i + 1 : i;
        int src1 = __shfl(idxv, ip, 32);
        float v1 = ea[(base + ip) * 32 + f];
        float h1 = h[(size_t)src1 * 32 + f];
        int buf = i & 1;
        stage[g][buf][f]      = v0;
        stage[g][buf][32 + f] = h0;
        // attention logit (same op order as K2 -> consistent exv)
        float acc = v0 * wfv;
#pragma unroll
        for (int m = 16; m >= 1; m >>= 1) acc += __shfl_xor(acc, m, 32);
        float4 qd = q4[dstn];
        float2 qs = q2[srcn];
        float exv   = __expf(leaky(qd.x + qs.x + acc));
        float alpha = exv / (qd.z + 1e-16f);
        float exv2  = __expf(leaky(qd.y + qs.y));
        float beta  = exv2 / (qd.w + 1e-16f);
        float coef  = alpha * beta;
        // three 32-dots: broadcast b128 reads + register weights
        float accE = 0.f, accR = 0.f, accH = 0.f;
        const float4* pe = (const float4*)&stage[g][buf][0];
        const float4* ph = (const float4*)&stage[g][buf][32];
#pragma unroll
        for (int q = 0; q < 8; ++q) {
            float4 evv = pe[q], hvv = ph[q];
            accE += evv.x * wfe[q*4] + evv.y * wfe[q*4+1] + evv.z * wfe[q*4+2] + evv.w * wfe[q*4+3];
            accR += evv.x * wre[q*4] + evv.y * wre[q*4+1] + evv.z * wre[q*4+2] + evv.w * wre[q*4+3];
            accH += hvv.x * weh[q*4] + hvv.y * weh[q*4+1] + hvv.z * weh[q*4+2] + hvv.w * weh[q*4+3];
        }
        eout[(base + i) * 32 + f] = coef * (accH + accE) + accR + bias;
        v0 = v1; h0 = h1;
    }
}

extern "C" void kernel_launch(void* const* d_in, const int* in_sizes, int n_in,
                              void* d_out, int out_size, void* d_ws, size_t ws_size,
                              hipStream_t stream) {
    const float* x         = (const float*)d_in[0];
    const int*   eidx      = (const int*)d_in[1];
    const float* ea        = (const float*)d_in[2];
    const float* W_lin     = (const float*)d_in[3];
    const float* W_le      = (const float*)d_in[4];
    const float* W_nattn   = (const float*)d_in[5];
    const float* W_nu      = (const float*)d_in[6];
    const float* W_out     = (const float*)d_in[7];
    const float* W_ea      = (const float*)d_in[8];
    const float* W_eu      = (const float*)d_in[9];
    const float* W_res     = (const float*)d_in[10];
    const float* W_re      = (const float*)d_in[11];
    const float* bias_node = (const float*)d_in[12];
    const float* bias_edge = (const float*)d_in[13];

    float* ws    = (float*)d_ws;
    float* aggr  = ws;                                 // N*64 (zeroed)
    float* sum   = aggr + (size_t)N_NODES * 64;        // N    (zeroed)
    float* h     = sum + N_NODES;                      // N*32
    float* a1    = h + (size_t)N_NODES * 32;           // N
    float* a2    = a1 + N_NODES;                       // N
    float* q2f   = a2 + N_NODES;                       // 2N
    float* q4f   = q2f + (size_t)N_NODES * 2;          // 4N
    float* wfold = q4f + (size_t)N_NODES * 4;          // 32
    float* Wnu_f = wfold + 32;                         // 1024
    float* Weu_f = Wnu_f + 1024;                       // 1024
    // total N*105 + 2080 floats ~= 42.0 MB

    float* xout = (float*)d_out;                       // N*32
    float* eout = xout + (size_t)N_NODES * 32;         // E*32

    int n4 = (N_NODES * 65) / 4;
    k_zero<<<2048, 256, 0, stream>>>((float4*)aggr, n4);
    k_fold<<<1, 1024, 0, stream>>>(W_le, W_nattn, W_nu, W_eu, wfold, Wnu_f, Weu_f);
    k_node_pre<<<N_NODES / 8, 256, 0, stream>>>(x, W_lin, W_res, W_nattn, h, xout, a1, a2);
    k_alpha_aggr<<<N_EDGES / 8, 256, 0, stream>>>(ea, eidx, a1, a2, wfold, h, sum, aggr);
    k_node_out<<<N_NODES / 8, 256, 0, stream>>>(aggr, sum, a1, a2, W_nu, Wnu_f, W_out, W_ea,
                                                bias_node, xout, (float4*)q4f, (float2*)q2f);
    k_beta<<<N_EDGES / 256, 256, 0, stream>>>(eidx, q4f, q2f, q4f);
    k_edge_final<<<N_EDGES / (8 * EPG), 256, 0, stream>>>(ea, eidx, W_re, Weu_f, W_eu, wfold,
                                                          h, (const float4*)q4f, (const float2*)q2f,
                                                          bias_edge, eout);
}

// Round 4
// 1129.367 us; speedup vs baseline: 1.5672x; 1.0951x over previous
//
#include <hip/hip_runtime.h>
#include <cstdint>
#include <cstddef>

#define N_NODES 100000
#define N_EDGES 1600000
#define EPG 16  // edges per 32-lane group in k_alpha_aggr / k_edge_final

__device__ __forceinline__ float leaky(float v) { return v > 0.f ? v : 0.2f * v; }

// ---- zero aggr32 + sum (contiguous N*33 floats) ----
__global__ __launch_bounds__(256) void k_zero(float* __restrict__ p, int n) {
    int i = blockIdx.x * 256 + threadIdx.x;
    int stride = gridDim.x * 256;
    for (; i < n; i += stride) p[i] = 0.f;
}

// ---- folds: wfold = W_le@W_nattn[64:], Wnu_f = W_le@W_nu[32:], Weu_f = W_le@W_eu[32:] ----
__global__ __launch_bounds__(1024) void k_fold(
    const float* __restrict__ W_le, const float* __restrict__ W_nattn,
    const float* __restrict__ W_nu, const float* __restrict__ W_eu,
    float* __restrict__ wfold, float* __restrict__ Wnu_f, float* __restrict__ Weu_f) {
    int t = threadIdx.x;
    int k = t >> 5, f = t & 31;
    float s1 = 0.f, s2 = 0.f, s0 = 0.f;
    for (int m = 0; m < 32; ++m) {
        float w = W_le[k * 32 + m];
        s1 += w * W_nu[(32 + m) * 32 + f];
        s2 += w * W_eu[(32 + m) * 32 + f];
        s0 += w * W_nattn[64 + m];
    }
    Wnu_f[k * 32 + f] = s1;
    Weu_f[k * 32 + f] = s2;
    if (f == 0) wfold[k] = s0;
}

// ---- K1: h = x@W_lin, res = x@W_res -> xout, a1 = h.w1, a2 = h.w2 ----
__global__ __launch_bounds__(256) void k_node_pre(
    const float* __restrict__ x, const float* __restrict__ W_lin,
    const float* __restrict__ W_res, const float* __restrict__ W_attn,
    float* __restrict__ h, float* __restrict__ xout,
    float* __restrict__ a1, float* __restrict__ a2) {
    __shared__ float Wl[64 * 32];
    __shared__ float Wr[64 * 32];
    __shared__ float xl[8][64];
    int tid = threadIdx.x;
    for (int i = tid; i < 64 * 32; i += 256) { Wl[i] = W_lin[i]; Wr[i] = W_res[i]; }
    __syncthreads();
    int f = tid & 31, nl = tid >> 5;
    int n = blockIdx.x * 8 + nl;
    xl[nl][f]      = x[(size_t)n * 64 + f];
    xl[nl][32 + f] = x[(size_t)n * 64 + 32 + f];
    float hf = 0.f, rf = 0.f;
#pragma unroll
    for (int k = 0; k < 64; ++k) {
        float xv = xl[nl][k];
        hf += xv * Wl[k * 32 + f];
        rf += xv * Wr[k * 32 + f];
    }
    h[(size_t)n * 32 + f]    = hf;
    xout[(size_t)n * 32 + f] = rf;
    float s1 = hf * W_attn[f];
    float s2 = hf * W_attn[32 + f];
#pragma unroll
    for (int m = 16; m >= 1; m >>= 1) {
        s1 += __shfl_xor(s1, m, 32);
        s2 += __shfl_xor(s2, m, 32);
    }
    if (f == 0) { a1[n] = s1; a2[n] = s2; }
}

// ---- K2: alpha + OUTPUT-SPACE aggregation ----
// m_e = h_src@W_nu_top + ea@Wnu_f (32-dim); aggr32[dst] += exv*m_e; sum[dst] += exv
__global__ __launch_bounds__(256) void k_alpha_aggr(
    const float* __restrict__ ea, const int* __restrict__ eidx,
    const float* __restrict__ a1, const float* __restrict__ a2,
    const float* __restrict__ wfold, const float* __restrict__ W_nu,
    const float* __restrict__ Wnu_f, const float* __restrict__ h,
    float* __restrict__ sum, float* __restrict__ aggr32) {
    __shared__ float stage[8][2][64];
    int tid = threadIdx.x;
    int f = tid & 31, g = tid >> 5;
    // weight columns in registers (64 VGPRs/lane)
    float wnh[32], wnf[32];
#pragma unroll
    for (int k = 0; k < 32; ++k) {
        wnh[k] = W_nu[k * 32 + f];     // top 32 rows of W_nu (h_j part)
        wnf[k] = Wnu_f[k * 32 + f];    // folded ea part
    }
    float wfv = wfold[f];
    size_t base = (size_t)(blockIdx.x * 8 + g) * EPG;
    // lanes 0..15: src ids of the 16 edges; lanes 16..31: dst ids
    int idxv = (f < 16) ? eidx[base + f] : eidx[N_EDGES + base + (f - 16)];
    int src0 = __shfl(idxv, 0, 32);
    float v0 = ea[base * 32 + f];
    float h0 = h[(size_t)src0 * 32 + f];
#pragma unroll 2
    for (int i = 0; i < EPG; ++i) {
        int srcn = __shfl(idxv, i, 32);
        int dstn = __shfl(idxv, 16 + i, 32);
        int ip = (i + 1 < EPG) ? i + 1 : i;
        int src1 = __shfl(idxv, ip, 32);
        float v1 = ea[(base + ip) * 32 + f];
        float h1 = h[(size_t)src1 * 32 + f];
        int buf = i & 1;
        stage[g][buf][f]      = v0;
        stage[g][buf][32 + f] = h0;
        // attention logit (op order matches k_edge_final)
        float acc = v0 * wfv;
#pragma unroll
        for (int m = 16; m >= 1; m >>= 1) acc += __shfl_xor(acc, m, 32);
        float exv = __expf(leaky(a1[dstn] + a2[srcn] + acc));
        // m_f = sum_k hj[k]*Wnu[k][f] + sum_k ea[k]*Wnu_f[k][f]
        float mf = 0.f;
        const float4* pe = (const float4*)&stage[g][buf][0];
        const float4* ph = (const float4*)&stage[g][buf][32];
#pragma unroll
        for (int q = 0; q < 8; ++q) {
            float4 evv = pe[q], hvv = ph[q];
            mf += hvv.x * wnh[q*4] + hvv.y * wnh[q*4+1] + hvv.z * wnh[q*4+2] + hvv.w * wnh[q*4+3];
            mf += evv.x * wnf[q*4] + evv.y * wnf[q*4+1] + evv.z * wnf[q*4+2] + evv.w * wnf[q*4+3];
        }
        atomicAdd(&aggr32[(size_t)dstn * 32 + f], exv * mf);
        if (f == 0) atomicAdd(&sum[dstn], exv);
        v0 = v1; h0 = h1;
    }
}

// ---- K4: node_out = aggr32/sum; xout += node_out + bias; b1,b2; pack q4/q2 ----
__global__ __launch_bounds__(256) void k_node_out(
    const float* __restrict__ aggr32, const float* __restrict__ sum,
    const float* __restrict__ a1, const float* __restrict__ a2,
    const float* __restrict__ W_out_, const float* __restrict__ W_ea,
    const float* __restrict__ bias_node,
    float* __restrict__ xout, float4* __restrict__ q4, float2* __restrict__ q2) {
    __shared__ float Wo[1024];
    __shared__ float nol[8][32];
    int tid = threadIdx.x;
    for (int i = tid; i < 1024; i += 256) Wo[i] = W_out_[i];
    __syncthreads();
    int f = tid & 31, nl = tid >> 5;
    int n = blockIdx.x * 8 + nl;
    float inv = 1.f / (sum[n] + 1e-16f);
    float nf = aggr32[(size_t)n * 32 + f] * inv;
    xout[(size_t)n * 32 + f] += nf + bias_node[f];
    nol[nl][f] = nf;
    float of = 0.f;
#pragma unroll
    for (int k = 0; k < 32; ++k) of += nol[nl][k] * Wo[k * 32 + f];
    float s1 = of * W_ea[f];
    float s2 = of * W_ea[32 + f];
#pragma unroll
    for (int m = 16; m >= 1; m >>= 1) {
        s1 += __shfl_xor(s1, m, 32);
        s2 += __shfl_xor(s2, m, 32);
    }
    if (f == 0) {
        q4[n] = make_float4(a1[n], s1, sum[n], 0.f);  // (a1, b1, sum, sum2=0)
        q2[n] = make_float2(a2[n], s2);               // (a2, b2)
    }
}

// ---- K5: beta denominator into q4[dst].w ----
__global__ __launch_bounds__(256) void k_beta(
    const int* __restrict__ eidx, const float* __restrict__ q4f,
    const float* __restrict__ q2f, float* __restrict__ q4w) {
    int e = blockIdx.x * 256 + threadIdx.x;
    int srcn = eidx[e], dstn = eidx[N_EDGES + e];
    float ex = __expf(leaky(q4f[(size_t)dstn * 4 + 1] + q2f[(size_t)srcn * 2 + 1]));
    atomicAdd(&q4w[(size_t)dstn * 4 + 3], ex);
}

// ---- K6: eout = alpha*beta*(h_j@Weu_top + ea@Weu_f) + ea@W_re + bias ----
__global__ __launch_bounds__(256) void k_edge_final(
    const float* __restrict__ ea, const int* __restrict__ eidx,
    const float* __restrict__ W_re, const float* __restrict__ Weu_f,
    const float* __restrict__ W_eu, const float* __restrict__ wfold,
    const float* __restrict__ h, const float4* __restrict__ q4,
    const float2* __restrict__ q2, const float* __restrict__ bias_edge,
    float* __restrict__ eout) {
    __shared__ float stage[8][2][64];
    int tid = threadIdx.x;
    int f = tid & 31, g = tid >> 5;
    float wre[32], wfe[32], weh[32];
#pragma unroll
    for (int k = 0; k < 32; ++k) {
        wre[k] = W_re[k * 32 + f];
        wfe[k] = Weu_f[k * 32 + f];
        weh[k] = W_eu[k * 32 + f];   // top 32 rows of W_eu
    }
    float wfv  = wfold[f];
    float bias = bias_edge[f];
    size_t base = (size_t)(blockIdx.x * 8 + g) * EPG;
    int idxv = (f < 16) ? eidx[base + f] : eidx[N_EDGES + base + (f - 16)];
    int src0 = __shfl(idxv, 0, 32);
    float v0 = ea[base * 32 + f];
    float h0 = h[(size_t)src0 * 32 + f];
#pragma unroll 2
    for (int i = 0; i < EPG; ++i) {
        int srcn = __shfl(idxv, i, 32);
        int dstn = __shfl(idxv, 16 + i, 32);
        int ip = (i + 1 < EPG) ? i + 1 : i;
        int src1 = __shfl(idxv, ip, 32);
        float v1 = ea[(base + ip) * 32 + f];
        float h1 = h[(size_t)src1 * 32 + f];
        int buf = i & 1;
        stage[g][buf][f]      = v0;
        stage[g][buf][32 + f] = h0;
        float acc = v0 * wfv;
#pragma unroll
        for (int m = 16; m >= 1; m >>= 1) acc += __shfl_xor(acc, m, 32);
        float4 qd = q4[dstn];
        float2 qs = q2[srcn];
        float exv   = __expf(leaky(qd.x + qs.x + acc));
        float alpha = exv / (qd.z + 1e-16f);
        float exv2  = __expf(leaky(qd.y + qs.y));
        float beta  = exv2 / (qd.w + 1e-16f);
        float coef  = alpha * beta;
        float accE = 0.f, accR = 0.f, accH = 0.f;
        const float4* pe = (const float4*)&stage[g][buf][0];
        const float4* ph = (const float4*)&stage[g][buf][32];
#pragma unroll
        for (int q = 0; q < 8; ++q) {
            float4 evv = pe[q], hvv = ph[q];
            accE += evv.x * wfe[q*4] + evv.y * wfe[q*4+1] + evv.z * wfe[q*4+2] + evv.w * wfe[q*4+3];
            accR += evv.x * wre[q*4] + evv.y * wre[q*4+1] + evv.z * wre[q*4+2] + evv.w * wre[q*4+3];
            accH += hvv.x * weh[q*4] + hvv.y * weh[q*4+1] + hvv.z * weh[q*4+2] + hvv.w * weh[q*4+3];
        }
        eout[(base + i) * 32 + f] = coef * (accH + accE) + accR + bias;
        v0 = v1; h0 = h1;
    }
}

extern "C" void kernel_launch(void* const* d_in, const int* in_sizes, int n_in,
                              void* d_out, int out_size, void* d_ws, size_t ws_size,
                              hipStream_t stream) {
    const float* x         = (const float*)d_in[0];
    const int*   eidx      = (const int*)d_in[1];
    const float* ea        = (const float*)d_in[2];
    const float* W_lin     = (const float*)d_in[3];
    const float* W_le      = (const float*)d_in[4];
    const float* W_nattn   = (const float*)d_in[5];
    const float* W_nu      = (const float*)d_in[6];
    const float* W_out     = (const float*)d_in[7];
    const float* W_ea      = (const float*)d_in[8];
    const float* W_eu      = (const float*)d_in[9];
    const float* W_res     = (const float*)d_in[10];
    const float* W_re      = (const float*)d_in[11];
    const float* bias_node = (const float*)d_in[12];
    const float* bias_edge = (const float*)d_in[13];

    float* ws     = (float*)d_ws;
    float* aggr32 = ws;                                // N*32 (zeroed)
    float* sum    = aggr32 + (size_t)N_NODES * 32;     // N    (zeroed)
    float* h      = sum + N_NODES;                     // N*32
    float* a1     = h + (size_t)N_NODES * 32;          // N
    float* a2     = a1 + N_NODES;                      // N
    float* q2f    = a2 + N_NODES;                      // 2N
    float* q4f    = q2f + (size_t)N_NODES * 2;         // 4N
    float* wfold  = q4f + (size_t)N_NODES * 4;         // 32
    float* Wnu_f  = wfold + 32;                        // 1024
    float* Weu_f  = Wnu_f + 1024;                      // 1024

    float* xout = (float*)d_out;                       // N*32
    float* eout = xout + (size_t)N_NODES * 32;         // E*32

    k_zero<<<1024, 256, 0, stream>>>(aggr32, N_NODES * 33);
    k_fold<<<1, 1024, 0, stream>>>(W_le, W_nattn, W_nu, W_eu, wfold, Wnu_f, Weu_f);
    k_node_pre<<<N_NODES / 8, 256, 0, stream>>>(x, W_lin, W_res, W_nattn, h, xout, a1, a2);
    k_alpha_aggr<<<N_EDGES / (8 * EPG), 256, 0, stream>>>(ea, eidx, a1, a2, wfold, W_nu, Wnu_f,
                                                          h, sum, aggr32);
    k_node_out<<<N_NODES / 8, 256, 0, stream>>>(aggr32, sum, a1, a2, W_out, W_ea,
                                                bias_node, xout, (float4*)q4f, (float2*)q2f);
    k_beta<<<N_EDGES / 256, 256, 0, stream>>>(eidx, q4f, q2f, q4f);
    k_edge_final<<<N_EDGES / (8 * EPG), 256, 0, stream>>>(ea, eidx, W_re, Weu_f, W_eu, wfold,
                                                          h, (const float4*)q4f, (const float2*)q2f,
                                                          bias_edge, eout);
}

// Round 5
// 843.736 us; speedup vs baseline: 2.0977x; 1.3385x over previous
//
#include <hip/hip_runtime.h>
#include <cstdint>
#include <cstddef>

#define N_NODES 100000
#define N_EDGES 1600000

typedef __attribute__((ext_vector_type(8))) short   s16x8;
typedef __attribute__((ext_vector_type(8))) __bf16  bf16x8;
typedef __attribute__((ext_vector_type(4))) float   f32x4;

__device__ __forceinline__ float leaky(float v) { return v > 0.f ? v : 0.2f * v; }

__device__ __forceinline__ unsigned short f2bf(float x) {
    unsigned int u = __float_as_uint(x);
    u += 0x7fffu + ((u >> 16) & 1u);           // RNE
    return (unsigned short)(u >> 16);
}
__device__ __forceinline__ bf16x8 ldbf8(const unsigned short* p) {
    s16x8 v = *(const s16x8*)p;
    return __builtin_bit_cast(bf16x8, v);
}
__device__ __forceinline__ bf16x8 packbf8(float4 a, float4 b) {
    s16x8 v;
    v[0]=(short)f2bf(a.x); v[1]=(short)f2bf(a.y); v[2]=(short)f2bf(a.z); v[3]=(short)f2bf(a.w);
    v[4]=(short)f2bf(b.x); v[5]=(short)f2bf(b.y); v[6]=(short)f2bf(b.z); v[7]=(short)f2bf(b.w);
    return __builtin_bit_cast(bf16x8, v);
}

// ---- zero aggr32 + sum (contiguous N*33 floats) ----
__global__ __launch_bounds__(256) void k_zero(float* __restrict__ p, int n) {
    int i = blockIdx.x * 256 + threadIdx.x;
    int stride = gridDim.x * 256;
    for (; i < n; i += stride) p[i] = 0.f;
}

// ---- folds + transposed bf16 weights ----
// wfold = W_le@W_nattn[64:] (fp32); WT[c][k] = W[k][c] in bf16 for the 5 matmul operands
__global__ __launch_bounds__(1024) void k_fold(
    const float* __restrict__ W_le, const float* __restrict__ W_nattn,
    const float* __restrict__ W_nu, const float* __restrict__ W_eu,
    const float* __restrict__ W_re,
    float* __restrict__ wfold,
    unsigned short* __restrict__ WnuTh, unsigned short* __restrict__ WnuTf,
    unsigned short* __restrict__ WeuTh, unsigned short* __restrict__ WeuTf,
    unsigned short* __restrict__ WreT) {
    int t = threadIdx.x;
    int k = t >> 5, f = t & 31;
    float s0 = 0.f, s1 = 0.f, s2 = 0.f;
    for (int m = 0; m < 32; ++m) {
        float w = W_le[k * 32 + m];
        s1 += w * W_nu[(32 + m) * 32 + f];
        s2 += w * W_eu[(32 + m) * 32 + f];
        s0 += w * W_nattn[64 + m];
    }
    WnuTf[f * 32 + k] = f2bf(s1);
    WeuTf[f * 32 + k] = f2bf(s2);
    WnuTh[f * 32 + k] = f2bf(W_nu[k * 32 + f]);
    WeuTh[f * 32 + k] = f2bf(W_eu[k * 32 + f]);
    WreT [f * 32 + k] = f2bf(W_re[k * 32 + f]);
    if (f == 0) wfold[k] = s0;
}

// ---- K1: h = x@W_lin (-> bf16), res = x@W_res -> xout, a1 = h.w1, a2 = h.w2 ----
__global__ __launch_bounds__(256) void k_node_pre(
    const float* __restrict__ x, const float* __restrict__ W_lin,
    const float* __restrict__ W_res, const float* __restrict__ W_attn,
    unsigned short* __restrict__ hbf, float* __restrict__ xout,
    float* __restrict__ a1, float* __restrict__ a2) {
    __shared__ float Wl[2048], Wr[2048];
    __shared__ float xl[8][64];
    int tid = threadIdx.x;
    for (int i = tid; i < 2048; i += 256) { Wl[i] = W_lin[i]; Wr[i] = W_res[i]; }
    __syncthreads();
    int f = tid & 31, nl = tid >> 5;
    int n = blockIdx.x * 8 + nl;
    xl[nl][f]      = x[(size_t)n * 64 + f];
    xl[nl][32 + f] = x[(size_t)n * 64 + 32 + f];
    float hf = 0.f, rf = 0.f;
#pragma unroll
    for (int k = 0; k < 64; ++k) {
        float xv = xl[nl][k];
        hf += xv * Wl[k * 32 + f];
        rf += xv * Wr[k * 32 + f];
    }
    hbf[(size_t)n * 32 + f]  = f2bf(hf);
    xout[(size_t)n * 32 + f] = rf;
    float s1 = hf * W_attn[f];
    float s2 = hf * W_attn[32 + f];
#pragma unroll
    for (int m = 16; m >= 1; m >>= 1) {
        s1 += __shfl_xor(s1, m, 32);
        s2 += __shfl_xor(s2, m, 32);
    }
    if (f == 0) { a1[n] = s1; a2[n] = s2; }
}

// ---- K2: MFMA alpha+aggregation. Per wave: 16 edges, m_e = hj@Wnu_top + ea@Wnu_f,
//          aggr32[dst] += exv*m_e (atomics), sum[dst] += exv ----
__global__ __launch_bounds__(256) void k_alpha_aggr(
    const float* __restrict__ ea, const int* __restrict__ eidx,
    const float* __restrict__ a1, const float* __restrict__ a2,
    const float* __restrict__ wfold, const unsigned short* __restrict__ hbf,
    const unsigned short* __restrict__ WnuTh, const unsigned short* __restrict__ WnuTf,
    float* __restrict__ sum, float* __restrict__ aggr32) {
    int tid = threadIdx.x;
    int l = tid & 63, wid = tid >> 6;
    int c = l & 15, kc = (l >> 4) * 8;
    bf16x8 B_h0 = ldbf8(&WnuTh[c * 32 + kc]);
    bf16x8 B_h1 = ldbf8(&WnuTh[(16 + c) * 32 + kc]);
    bf16x8 B_f0 = ldbf8(&WnuTf[c * 32 + kc]);
    bf16x8 B_f1 = ldbf8(&WnuTf[(16 + c) * 32 + kc]);
    size_t base = (size_t)(blockIdx.x * 4 + wid) * 16;
    int em = (int)base + c;                 // this lane's edge (row c)
    int srcn = eidx[em], dstn = eidx[N_EDGES + em];
    const float4* pe = (const float4*)&ea[(size_t)em * 32 + kc];
    float4 e0 = pe[0], e1 = pe[1];
    bf16x8 Ae = packbf8(e0, e1);
    bf16x8 Ah = ldbf8(&hbf[(size_t)srcn * 32 + kc]);
    // fp32 attention logit: partial dot over this lane's k-chunk, reduce over 4 k-groups
    float4 w0 = *(const float4*)&wfold[kc];
    float4 w1 = *(const float4*)&wfold[kc + 4];
    float pd = e0.x*w0.x + e0.y*w0.y + e0.z*w0.z + e0.w*w0.w
             + e1.x*w1.x + e1.y*w1.y + e1.z*w1.z + e1.w*w1.w;
    pd += __shfl_xor(pd, 16, 64);
    pd += __shfl_xor(pd, 32, 64);
    float exv = __expf(leaky(a1[dstn] + a2[srcn] + pd));
    f32x4 z = {0.f, 0.f, 0.f, 0.f};
    f32x4 M0 = z, M1 = z;
    M0 = __builtin_amdgcn_mfma_f32_16x16x32_bf16(Ah, B_h0, M0, 0, 0, 0);
    M0 = __builtin_amdgcn_mfma_f32_16x16x32_bf16(Ae, B_f0, M0, 0, 0, 0);
    M1 = __builtin_amdgcn_mfma_f32_16x16x32_bf16(Ah, B_h1, M1, 0, 0, 0);
    M1 = __builtin_amdgcn_mfma_f32_16x16x32_bf16(Ae, B_f1, M1, 0, 0, 0);
    if ((l >> 4) == 0) atomicAdd(&sum[dstn], exv);
    int r0 = (l >> 4) * 4;
#pragma unroll
    for (int j = 0; j < 4; ++j) {
        int r = r0 + j;
        int   dr = __shfl(dstn, r, 64);
        float er = __shfl(exv,  r, 64);
        atomicAdd(&aggr32[(size_t)dr * 32 + c],      er * M0[j]);
        atomicAdd(&aggr32[(size_t)dr * 32 + 16 + c], er * M1[j]);
    }
}

// ---- K4: node_out = aggr32/sum; xout += node_out + bias; b1,b2; pack q4/q2 ----
__global__ __launch_bounds__(256) void k_node_out(
    const float* __restrict__ aggr32, const float* __restrict__ sum,
    const float* __restrict__ a1, const float* __restrict__ a2,
    const float* __restrict__ W_out_, const float* __restrict__ W_ea,
    const float* __restrict__ bias_node,
    float* __restrict__ xout, float4* __restrict__ q4, float2* __restrict__ q2) {
    __shared__ float Wo[1024];
    __shared__ float nol[8][32];
    int tid = threadIdx.x;
    for (int i = tid; i < 1024; i += 256) Wo[i] = W_out_[i];
    __syncthreads();
    int f = tid & 31, nl = tid >> 5;
    int n = blockIdx.x * 8 + nl;
    float inv = 1.f / (sum[n] + 1e-16f);
    float nf = aggr32[(size_t)n * 32 + f] * inv;
    xout[(size_t)n * 32 + f] += nf + bias_node[f];
    nol[nl][f] = nf;
    float of = 0.f;
#pragma unroll
    for (int k = 0; k < 32; ++k) of += nol[nl][k] * Wo[k * 32 + f];
    float s1 = of * W_ea[f];
    float s2 = of * W_ea[32 + f];
#pragma unroll
    for (int m = 16; m >= 1; m >>= 1) {
        s1 += __shfl_xor(s1, m, 32);
        s2 += __shfl_xor(s2, m, 32);
    }
    if (f == 0) {
        q4[n] = make_float4(a1[n], s1, sum[n], 0.f);  // (a1, b1, sum, sum2=0)
        q2[n] = make_float2(a2[n], s2);               // (a2, b2)
    }
}

// ---- K5: beta denominator into q4[dst].w ----
__global__ __launch_bounds__(256) void k_beta(
    const int* __restrict__ eidx, const float* __restrict__ q4f,
    const float* __restrict__ q2f, float* __restrict__ q4w) {
    int e = blockIdx.x * 256 + threadIdx.x;
    int srcn = eidx[e], dstn = eidx[N_EDGES + e];
    float ex = __expf(leaky(q4f[(size_t)dstn * 4 + 1] + q2f[(size_t)srcn * 2 + 1]));
    atomicAdd(&q4w[(size_t)dstn * 4 + 3], ex);
}

// ---- K6: MFMA edge output: eout = coef*(hj@Weu_top + ea@Weu_f) + ea@W_re + bias ----
__global__ __launch_bounds__(256) void k_edge_final(
    const float* __restrict__ ea, const int* __restrict__ eidx,
    const unsigned short* __restrict__ hbf,
    const unsigned short* __restrict__ WeuTh, const unsigned short* __restrict__ WeuTf,
    const unsigned short* __restrict__ WreT, const float* __restrict__ wfold,
    const float4* __restrict__ q4, const float2* __restrict__ q2,
    const float* __restrict__ bias_edge, float* __restrict__ eout) {
    int tid = threadIdx.x;
    int l = tid & 63, wid = tid >> 6;
    int c = l & 15, kc = (l >> 4) * 8;
    bf16x8 B_h0 = ldbf8(&WeuTh[c * 32 + kc]);
    bf16x8 B_h1 = ldbf8(&WeuTh[(16 + c) * 32 + kc]);
    bf16x8 B_f0 = ldbf8(&WeuTf[c * 32 + kc]);
    bf16x8 B_f1 = ldbf8(&WeuTf[(16 + c) * 32 + kc]);
    bf16x8 B_r0 = ldbf8(&WreT[c * 32 + kc]);
    bf16x8 B_r1 = ldbf8(&WreT[(16 + c) * 32 + kc]);
    float bias0 = bias_edge[c], bias1 = bias_edge[16 + c];
    size_t base = (size_t)(blockIdx.x * 4 + wid) * 16;
    int em = (int)base + c;
    int srcn = eidx[em], dstn = eidx[N_EDGES + em];
    const float4* pe = (const float4*)&ea[(size_t)em * 32 + kc];
    float4 e0 = pe[0], e1 = pe[1];
    bf16x8 Ae = packbf8(e0, e1);
    bf16x8 Ah = ldbf8(&hbf[(size_t)srcn * 32 + kc]);
    // fp32 logit (identical op order to K2 -> bit-identical exv)
    float4 w0 = *(const float4*)&wfold[kc];
    float4 w1 = *(const float4*)&wfold[kc + 4];
    float pd = e0.x*w0.x + e0.y*w0.y + e0.z*w0.z + e0.w*w0.w
             + e1.x*w1.x + e1.y*w1.y + e1.z*w1.z + e1.w*w1.w;
    pd += __shfl_xor(pd, 16, 64);
    pd += __shfl_xor(pd, 32, 64);
    float4 qd = q4[dstn];
    float2 qs = q2[srcn];
    float exv   = __expf(leaky(qd.x + qs.x + pd));
    float alpha = exv / (qd.z + 1e-16f);
    float exv2  = __expf(leaky(qd.y + qs.y));
    float beta  = exv2 / (qd.w + 1e-16f);
    float coef  = alpha * beta;
    f32x4 z = {0.f, 0.f, 0.f, 0.f};
    f32x4 P0 = z, P1 = z, R0 = z, R1 = z;
    P0 = __builtin_amdgcn_mfma_f32_16x16x32_bf16(Ah, B_h0, P0, 0, 0, 0);
    P0 = __builtin_amdgcn_mfma_f32_16x16x32_bf16(Ae, B_f0, P0, 0, 0, 0);
    P1 = __builtin_amdgcn_mfma_f32_16x16x32_bf16(Ah, B_h1, P1, 0, 0, 0);
    P1 = __builtin_amdgcn_mfma_f32_16x16x32_bf16(Ae, B_f1, P1, 0, 0, 0);
    R0 = __builtin_amdgcn_mfma_f32_16x16x32_bf16(Ae, B_r0, R0, 0, 0, 0);
    R1 = __builtin_amdgcn_mfma_f32_16x16x32_bf16(Ae, B_r1, R1, 0, 0, 0);
    int r0 = (l >> 4) * 4;
#pragma unroll
    for (int j = 0; j < 4; ++j) {
        int r = r0 + j;
        float cf = __shfl(coef, r, 64);
        size_t row = (base + r) * 32;
        eout[row + c]      = cf * P0[j] + R0[j] + bias0;
        eout[row + 16 + c] = cf * P1[j] + R1[j] + bias1;
    }
}

extern "C" void kernel_launch(void* const* d_in, const int* in_sizes, int n_in,
                              void* d_out, int out_size, void* d_ws, size_t ws_size,
                              hipStream_t stream) {
    const float* x         = (const float*)d_in[0];
    const int*   eidx      = (const int*)d_in[1];
    const float* ea        = (const float*)d_in[2];
    const float* W_lin     = (const float*)d_in[3];
    const float* W_le      = (const float*)d_in[4];
    const float* W_nattn   = (const float*)d_in[5];
    const float* W_nu      = (const float*)d_in[6];
    const float* W_out     = (const float*)d_in[7];
    const float* W_ea      = (const float*)d_in[8];
    const float* W_eu      = (const float*)d_in[9];
    const float* W_res     = (const float*)d_in[10];
    const float* W_re      = (const float*)d_in[11];
    const float* bias_node = (const float*)d_in[12];
    const float* bias_edge = (const float*)d_in[13];

    float* ws     = (float*)d_ws;
    float* aggr32 = ws;                                  // 32N (zeroed)
    float* sum    = aggr32 + (size_t)N_NODES * 32;       // N   (zeroed)
    float* a1     = sum + N_NODES;                       // N
    float* a2     = a1 + N_NODES;                        // N
    float* q4f    = a2 + N_NODES;                        // 4N  (16B-aligned: 35N*4 % 16 == 0)
    float* q2f    = q4f + (size_t)N_NODES * 4;           // 2N
    float* wfold  = q2f + (size_t)N_NODES * 2;           // 32
    unsigned short* hbf   = (unsigned short*)(wfold + 32);   // 32N bf16
    unsigned short* WnuTh = hbf + (size_t)N_NODES * 32;      // 1024 each
    unsigned short* WnuTf = WnuTh + 1024;
    unsigned short* WeuTh = WnuTf + 1024;
    unsigned short* WeuTf = WeuTh + 1024;
    unsigned short* WreT  = WeuTf + 1024;
    // ~23 MB total

    float* xout = (float*)d_out;                         // N*32
    float* eout = xout + (size_t)N_NODES * 32;           // E*32

    k_zero<<<1024, 256, 0, stream>>>(aggr32, N_NODES * 33);
    k_fold<<<1, 1024, 0, stream>>>(W_le, W_nattn, W_nu, W_eu, W_re,
                                   wfold, WnuTh, WnuTf, WeuTh, WeuTf, WreT);
    k_node_pre<<<N_NODES / 8, 256, 0, stream>>>(x, W_lin, W_res, W_nattn, hbf, xout, a1, a2);
    k_alpha_aggr<<<N_EDGES / 64, 256, 0, stream>>>(ea, eidx, a1, a2, wfold, hbf,
                                                   WnuTh, WnuTf, sum, aggr32);
    k_node_out<<<N_NODES / 8, 256, 0, stream>>>(aggr32, sum, a1, a2, W_out, W_ea,
                                                bias_node, xout, (float4*)q4f, (float2*)q2f);
    k_beta<<<N_EDGES / 256, 256, 0, stream>>>(eidx, q4f, q2f, q4f);
    k_edge_final<<<N_EDGES / 64, 256, 0, stream>>>(ea, eidx, hbf, WeuTh, WeuTf, WreT, wfold,
                                                   (const float4*)q4f, (const float2*)q2f,
                                                   bias_edge, eout);
}